// Round 3
// baseline (2997.787 us; speedup 1.0000x reference)
//
#include <hip/hip_runtime.h>
#include <stdint.h>

// Problem constants: B=8, N=4096, D=256, F=1024
#define TM 128
#define TN 128
#define TKD 16

__device__ __forceinline__ float4 ld4(const float* p){ return *reinterpret_cast<const float4*>(p); }

// Generic tiled f32 GEMM: C[i,j] = sum_k A[i,k]*B[k,j]  (logical)
// AL: 0 = A f32 row-major [i][k]; 1 = A u8 stored [k][i] (transposed access); 2 = A u8 row-major [i][k]
// BL: 0 = B f32 stored [j][k] (A·B^T form); 1 = B f32 stored [k][j]
// EPI: 0 = C=acc+bias[j]
//      1 = hg u8 = (v1[i]+v2[j]-2*acc < 529)
//      2 = C=acc*norm(v1[i]) + resid[i*ldc+j]   (norm = v1>0 ? 1/v1 : 0)
//      3 = C=relu(acc+bias[j])
//      4 = C=acc+bias[j]+resid[i*ldc+j]
template<int AL, int BL, int EPI>
__global__ __launch_bounds__(256)
void gemm_k(const void* __restrict__ Ap, const float* __restrict__ Bp,
            void* __restrict__ Cp,
            int M, int Nn, int K, int lda, int ldb, int ldc,
            long long sA, long long sB, long long sC,
            const float* __restrict__ bias,
            const float* __restrict__ v1, long long sv1,
            const float* __restrict__ v2, long long sv2,
            const float* __restrict__ resid, long long sR)
{
    __shared__ float As[TKD][TM+4];
    __shared__ float Bs[TKD][TN+4];
    const int t  = threadIdx.x;
    const int tx = t & 15, ty = t >> 4;
    const int i0 = blockIdx.x * TM, j0 = blockIdx.y * TN;
    const int z  = blockIdx.z;

    const float*   Af = (const float*)Ap   + (AL==0 ? (size_t)z*sA : (size_t)0);
    const uint8_t* Au = (const uint8_t*)Ap + (AL!=0 ? (size_t)z*sA : (size_t)0);
    const float*   B  = Bp + (size_t)z*sB;
    const float*   v1z = v1 ? v1 + (size_t)z*sv1 : nullptr;
    const float*   v2z = v2 ? v2 + (size_t)z*sv2 : nullptr;
    const float*   rz  = resid ? resid + (size_t)z*sR : nullptr;

    float acc[8][8];
    #pragma unroll
    for (int i=0;i<8;++i)
        #pragma unroll
        for (int j=0;j<8;++j) acc[i][j]=0.f;

    for (int k0 = 0; k0 < K; k0 += TKD) {
        // ---- stage A tile into As[k][i]
        if constexpr (AL == 0) {
            const int ti = t >> 1, tk8 = (t & 1) * 8;
            const float* ap = Af + (size_t)(i0+ti)*lda + k0 + tk8;
            float4 a0 = ld4(ap), a1 = ld4(ap+4);
            As[tk8+0][ti]=a0.x; As[tk8+1][ti]=a0.y; As[tk8+2][ti]=a0.z; As[tk8+3][ti]=a0.w;
            As[tk8+4][ti]=a1.x; As[tk8+5][ti]=a1.y; As[tk8+6][ti]=a1.z; As[tk8+7][ti]=a1.w;
        } else if constexpr (AL == 1) {
            const int tk = t >> 4, ti8 = (t & 15) * 8;
            uint64_t w = *(const uint64_t*)(Au + (size_t)(k0+tk)*lda + i0 + ti8);
            #pragma unroll
            for (int c=0;c<8;++c) As[tk][ti8+c] = (float)((w >> (8*c)) & 0xFF);
        } else {
            const int ti = t >> 1, tk8 = (t & 1) * 8;
            uint64_t w = *(const uint64_t*)(Au + (size_t)(i0+ti)*lda + k0 + tk8);
            #pragma unroll
            for (int c=0;c<8;++c) As[tk8+c][ti] = (float)((w >> (8*c)) & 0xFF);
        }
        // ---- stage B tile into Bs[k][j]
        if constexpr (BL == 0) {
            const int tj = t >> 1, tk8 = (t & 1) * 8;
            const float* bp = B + (size_t)(j0+tj)*ldb + k0 + tk8;
            float4 b0 = ld4(bp), b1 = ld4(bp+4);
            Bs[tk8+0][tj]=b0.x; Bs[tk8+1][tj]=b0.y; Bs[tk8+2][tj]=b0.z; Bs[tk8+3][tj]=b0.w;
            Bs[tk8+4][tj]=b1.x; Bs[tk8+5][tj]=b1.y; Bs[tk8+6][tj]=b1.z; Bs[tk8+7][tj]=b1.w;
        } else {
            const int tk = t >> 4, tj8 = (t & 15) * 8;
            const float* bp = B + (size_t)(k0+tk)*ldb + j0 + tj8;
            *(float4*)&Bs[tk][tj8]   = ld4(bp);
            *(float4*)&Bs[tk][tj8+4] = ld4(bp+4);
        }
        __syncthreads();
        #pragma unroll
        for (int k=0;k<TKD;++k) {
            float av[8], bv[8];
            *(float4*)&av[0] = *(const float4*)&As[k][ty*8];
            *(float4*)&av[4] = *(const float4*)&As[k][ty*8+4];
            *(float4*)&bv[0] = *(const float4*)&Bs[k][tx*8];
            *(float4*)&bv[4] = *(const float4*)&Bs[k][tx*8+4];
            #pragma unroll
            for (int i=0;i<8;++i)
                #pragma unroll
                for (int j=0;j<8;++j)
                    acc[i][j] = fmaf(av[i], bv[j], acc[i][j]);
        }
        __syncthreads();
    }

    const int r0 = i0 + ty*8, c0 = j0 + tx*8;
    if constexpr (EPI == 1) {
        uint8_t* Cu = (uint8_t*)Cp + (size_t)z*sC;
        float n1r[8], n2c[8];
        #pragma unroll
        for (int i=0;i<8;++i) n1r[i] = v1z[r0+i];
        #pragma unroll
        for (int j=0;j<8;++j) n2c[j] = v2z[c0+j];
        #pragma unroll
        for (int i=0;i<8;++i) {
            uint8_t* cp = Cu + (size_t)(r0+i)*ldc + c0;
            uchar4 p0, p1;
            p0.x = (uint8_t)((n1r[i]+n2c[0]-2.f*acc[i][0]) < 529.f);
            p0.y = (uint8_t)((n1r[i]+n2c[1]-2.f*acc[i][1]) < 529.f);
            p0.z = (uint8_t)((n1r[i]+n2c[2]-2.f*acc[i][2]) < 529.f);
            p0.w = (uint8_t)((n1r[i]+n2c[3]-2.f*acc[i][3]) < 529.f);
            p1.x = (uint8_t)((n1r[i]+n2c[4]-2.f*acc[i][4]) < 529.f);
            p1.y = (uint8_t)((n1r[i]+n2c[5]-2.f*acc[i][5]) < 529.f);
            p1.z = (uint8_t)((n1r[i]+n2c[6]-2.f*acc[i][6]) < 529.f);
            p1.w = (uint8_t)((n1r[i]+n2c[7]-2.f*acc[i][7]) < 529.f);
            *(uchar4*)cp     = p0;
            *(uchar4*)(cp+4) = p1;
        }
    } else {
        float* C = (float*)Cp + (size_t)z*sC;
        float bb[8];
        if constexpr (EPI == 0 || EPI == 3 || EPI == 4) {
            #pragma unroll
            for (int j=0;j<8;++j) bb[j] = bias[c0+j];
        }
        #pragma unroll
        for (int i=0;i<8;++i) {
            float* cp = C + (size_t)(r0+i)*ldc + c0;
            float o[8];
            if constexpr (EPI == 0) {
                #pragma unroll
                for (int j=0;j<8;++j) o[j] = acc[i][j] + bb[j];
            } else if constexpr (EPI == 2) {
                float d = v1z[r0+i];
                float nrm = d > 0.f ? 1.f/d : 0.f;
                const float* rp = rz + (size_t)(r0+i)*ldc + c0;
                #pragma unroll
                for (int j=0;j<8;++j) o[j] = acc[i][j]*nrm + rp[j];
            } else if constexpr (EPI == 3) {
                #pragma unroll
                for (int j=0;j<8;++j) { float v = acc[i][j] + bb[j]; o[j] = v > 0.f ? v : 0.f; }
            } else { // EPI == 4
                const float* rp = rz + (size_t)(r0+i)*ldc + c0;
                #pragma unroll
                for (int j=0;j<8;++j) o[j] = acc[i][j] + bb[j] + rp[j];
            }
            *(float4*)cp     = *(float4*)&o[0];
            *(float4*)(cp+4) = *(float4*)&o[4];
        }
    }
}

// row squared-norms for ind (-> n1) and disc (-> n2); rows = B*N, D=256
__global__ __launch_bounds__(256)
void rownorm_k(const float* __restrict__ ind, const float* __restrict__ disc,
               float* __restrict__ n1, float* __restrict__ n2, int rows)
{
    int wid = threadIdx.x >> 6, lane = threadIdx.x & 63;
    int r = blockIdx.x * 4 + wid;
    const float* src; float* dst; int rr;
    if (r < rows) { src = ind;  dst = n1; rr = r; }
    else          { src = disc; dst = n2; rr = r - rows; }
    float4 v = ld4(src + (size_t)rr*256 + lane*4);
    float s = v.x*v.x + v.y*v.y + v.z*v.z + v.w*v.w;
    #pragma unroll
    for (int o=32;o;o>>=1) s += __shfl_down(s, o);
    if (lane == 0) dst[rr] = s;
}

// degN[row] = sum over e of hg[row][e]  (row = b*N+n), N=4096
__global__ __launch_bounds__(256)
void degN_k(const uint8_t* __restrict__ hg, float* __restrict__ degN)
{
    size_t row = blockIdx.x;
    int t = threadIdx.x;
    const uint8_t* p = hg + row*4096;
    int s = 0;
    #pragma unroll
    for (int it=0; it<16; ++it) s += p[it*256 + t];
    int lane = t & 63, wid = t >> 6;
    #pragma unroll
    for (int o=32;o;o>>=1) s += __shfl_down(s, o);
    __shared__ int red[4];
    if (lane == 0) red[wid] = s;
    __syncthreads();
    if (t == 0) degN[row] = (float)(red[0]+red[1]+red[2]+red[3]);
}

// degE[b*N+e] += partial column sums of hg  (requires degE zeroed)
__global__ __launch_bounds__(256)
void degE_k(const uint8_t* __restrict__ hg, float* __restrict__ degE)
{
    int b = blockIdx.x >> 4, cc = blockIdx.x & 15, rc = blockIdx.y;
    int e = cc*256 + threadIdx.x;
    const uint8_t* p = hg + ((size_t)b*4096 + (size_t)rc*256)*4096 + e;
    int s = 0;
    for (int n=0;n<256;++n) s += p[(size_t)n*4096];
    atomicAdd(&degE[(size_t)b*4096 + e], (float)s);
}

// LayerNorm over D=256 per row
__global__ __launch_bounds__(256)
void ln_k(const float* __restrict__ q, const float* __restrict__ g,
          const float* __restrict__ bta, float* __restrict__ out)
{
    size_t row = blockIdx.x;
    int t = threadIdx.x;
    float x = q[row*256 + t];
    float s1 = x, s2 = x*x;
    int lane = t & 63, wid = t >> 6;
    #pragma unroll
    for (int o=32;o;o>>=1) { s1 += __shfl_down(s1,o); s2 += __shfl_down(s2,o); }
    __shared__ float a1[4], a2[4];
    if (lane == 0) { a1[wid]=s1; a2[wid]=s2; }
    __syncthreads();
    s1 = a1[0]+a1[1]+a1[2]+a1[3];
    s2 = a2[0]+a2[1]+a2[2]+a2[3];
    float mu  = s1 * (1.f/256.f);
    float var = s2 * (1.f/256.f) - mu*mu;
    float r = rsqrtf(var + 1e-5f);
    out[row*256 + t] = (x - mu) * r * g[t] + bta[t];
}

extern "C" void kernel_launch(void* const* d_in, const int* in_sizes, int n_in,
                              void* d_out, int out_size, void* d_ws, size_t ws_size,
                              hipStream_t stream)
{
    const float* disc = (const float*)d_in[0];
    const float* ind  = (const float*)d_in[1];
    const float* W_fc = (const float*)d_in[2];
    const float* b_fc = (const float*)d_in[3];
    const float* W1   = (const float*)d_in[4];
    const float* b1   = (const float*)d_in[5];
    const float* W2   = (const float*)d_in[6];
    const float* b2   = (const float*)d_in[7];
    const float* ln_g = (const float*)d_in[8];
    const float* ln_b = (const float*)d_in[9];
    float* out = (float*)d_out;

    const int B = 8, N = 4096, D = 256, F = 1024, BN = B*N;

    // workspace layout (bytes); total ~225 MB
    char* ws = (char*)d_ws;
    uint8_t* hg  = (uint8_t*)ws;                         // 134,217,728 (B*N*N u8)
    float*   X   = (float*)(ws + 134217728);             // 33,554,432
    float*   E   = (float*)(ws + 167772160);             // 33,554,432
    float*   enh = (float*)(ws + 201326592);             // 33,554,432
    float*   n1  = (float*)(ws + 234881024);             // 131,072
    float*   n2  = (float*)(ws + 235012096);             // 131,072
    float*   dN  = (float*)(ws + 235143168);             // 131,072
    float*   dE  = (float*)(ws + 235274240);             // 131,072
    float*   h   = (float*)ws;                           // aliases hg (dead after agg2)
    float*   q   = E;                                    // aliases E  (dead after agg2)

    hipMemsetAsync(dE, 0, (size_t)BN*4, stream);

    rownorm_k<<<BN*2/4, 256, 0, stream>>>(ind, disc, n1, n2, BN);

    // X = ind @ W_fc^T + b_fc   [BN x 256]
    gemm_k<0,0,0><<<dim3(BN/TM, D/TN, 1), 256, 0, stream>>>(
        ind, W_fc, X, BN, D, D, D, D, D, 0, 0, 0,
        b_fc, nullptr, 0, nullptr, 0, nullptr, 0);

    // hg[b,n,m] = (|f1_n|^2 + |f2_m|^2 - 2 f1_n.f2_m < 529)
    gemm_k<0,0,1><<<dim3(N/TM, N/TN, B), 256, 0, stream>>>(
        ind, disc, hg, N, N, D, D, D, N,
        (long long)N*D, (long long)N*D, (long long)N*N,
        nullptr, n1, N, n2, N, nullptr, 0);

    degN_k<<<BN, 256, 0, stream>>>(hg, dN);
    degE_k<<<dim3(B*16, 16, 1), 256, 0, stream>>>(hg, dE);

    // E = (hg^T @ X) * normE + disc   [per batch: 4096 x 256, K=4096]
    gemm_k<1,1,2><<<dim3(N/TM, D/TN, B), 256, 0, stream>>>(
        hg, X, E, N, D, N, N, D, D,
        (long long)N*N, (long long)N*D, (long long)N*D,
        nullptr, dE, N, nullptr, 0, disc, (long long)N*D);

    // enh = (hg @ E) * normN + ind
    gemm_k<2,1,2><<<dim3(N/TM, D/TN, B), 256, 0, stream>>>(
        hg, E, enh, N, D, N, N, D, D,
        (long long)N*N, (long long)N*D, (long long)N*D,
        nullptr, dN, N, nullptr, 0, ind, (long long)N*D);

    // h = relu(enh @ W1^T + b1)   [BN x 1024]
    gemm_k<0,0,3><<<dim3(BN/TM, F/TN, 1), 256, 0, stream>>>(
        enh, W1, h, BN, F, D, D, D, F, 0, 0, 0,
        b1, nullptr, 0, nullptr, 0, nullptr, 0);

    // q = h @ W2^T + b2 + enh   [BN x 256]
    gemm_k<0,0,4><<<dim3(BN/TM, D/TN, 1), 256, 0, stream>>>(
        h, W2, q, BN, D, F, F, F, D, 0, 0, 0,
        b2, nullptr, 0, nullptr, 0, enh, 0);

    ln_k<<<BN, 256, 0, stream>>>(q, ln_g, ln_b, out);
}

// Round 4
// 929.773 us; speedup vs baseline: 3.2242x; 3.2242x over previous
//
#include <hip/hip_runtime.h>
#include <stdint.h>

// B=8, N=4096, D=256, F=1024.  All GEMMs on MFMA 16x16x32 bf16, 128x128 tiles,
// 4 waves/block, global_load_lds staging.  hg kept BIT-PACKED in both
// orientations (16.8MB each -> L3-resident aggregations).
// Gram uses hi/lo split-bf16 (3 MFMA) to preserve f32-level threshold accuracy.

typedef unsigned short u16;
typedef __attribute__((ext_vector_type(8))) short bf16x8;   // 8 bf16 = 4 VGPR
typedef __attribute__((ext_vector_type(4))) float f32x4;

#define GLDS(g, l) __builtin_amdgcn_global_load_lds((const __attribute__((address_space(1))) void*)(g), (__attribute__((address_space(3))) void*)(l), 16, 0, 0)

__device__ __forceinline__ float4 ld4(const float* p){ return *reinterpret_cast<const float4*>(p); }
__device__ __forceinline__ u16 f2bf(float f){
    union{float f;unsigned u;}x{f};
    unsigned r=(x.u+0x7FFFu+((x.u>>16)&1u))>>16; return (u16)r;
}
__device__ __forceinline__ float bf2f(u16 s){
    union{unsigned u;float f;}x{(unsigned)s<<16}; return x.f;
}

// ---------------------------------------------------------------------------
// Unified MFMA GEMM.  C[i,j] = sum_k A[i,k]*B[k,j].
// A staged from [M][K] rows (bf16), or bit-packed rows (ABITS: lda in u16-chunks).
// Bt staged from [N][K] rows (bf16) i.e. B^T-layout, or bit-packed (BBITS).
// SPLIT: A2/B2 are lo-parts; acc += A*B2 + A2*B (3 MFMA / frag).
// EPI: 0: C_bf = acc + bias[row]            (XT projection)
//      1: hg bitpack dual-write (ballot)    (gram, needs v1 row / v2 col norms)
//      2: C_bf = acc*nrm(v2[col]) + bf(Rb)  (agg1 -> E^T)
//      3: Cf = acc*nrm(v1[row]) + Rf ; C2_bf = same  (agg2 -> enh)
//      4: C_bf = relu(acc + bias[col])      (FFN1)
//      5: Cf = acc + bias[col] + Rf         (FFN2)
// ---------------------------------------------------------------------------
template<int EPI, bool SPLIT, bool ABITS, bool BBITS>
__global__ __launch_bounds__(256)
void mg(const u16* __restrict__ A, const u16* __restrict__ A2,
        const u16* __restrict__ Bt, const u16* __restrict__ B2,
        void* __restrict__ C, void* __restrict__ C2,
        int K, int lda, int ldb, int ldc,
        long long sA, long long sB, long long sC, long long sC2,
        const float* __restrict__ bias,
        const float* __restrict__ v1, long long sv1,
        const float* __restrict__ v2, long long sv2,
        const void* __restrict__ resid, long long sR)
{
    __shared__ u16 As[4096], Bs[4096];
    __shared__ u16 As2[SPLIT ? 4096 : 8], Bs2[SPLIT ? 4096 : 8];
    const int t = threadIdx.x, lane = t & 63, wv = t >> 6;
    const int i0 = blockIdx.x*128, j0 = blockIdx.y*128, z = blockIdx.z;
    const int wr = (wv>>1)*64, wc = (wv&1)*64;

    const u16* Az  = A  + (size_t)z*sA;
    const u16* Bz  = Bt + (size_t)z*sB;
    const u16* A2z = SPLIT ? A2 + (size_t)z*sA : nullptr;
    const u16* B2z = SPLIT ? B2 + (size_t)z*sB : nullptr;

    f32x4 zero4 = {0.f,0.f,0.f,0.f};
    f32x4 acc[4][4];
    #pragma unroll
    for (int m=0;m<4;++m)
        #pragma unroll
        for (int n=0;n<4;++n) acc[m][n] = zero4;

    for (int k0 = 0; k0 < K; k0 += 32) {
        // ---- stage A tile [128 rows][32 k] bf16 into As
        if constexpr (ABITS) {
            const int row = t & 127, half = t >> 7;
            unsigned v = Az[(size_t)(i0+row)*lda + (k0>>4) + half];
            u16* p = As + row*32 + half*16;
            uint4 w0, w1;
            #define PK(i) ((((v)>>(i))&1u)*0x3F80u | (((v)>>((i)+1))&1u)*0x3F800000u)
            w0.x=PK(0);  w0.y=PK(2);  w0.z=PK(4);  w0.w=PK(6);
            w1.x=PK(8);  w1.y=PK(10); w1.z=PK(12); w1.w=PK(14);
            *(uint4*)p = w0; *(uint4*)(p+8) = w1;
        } else {
            #pragma unroll
            for (int q=0;q<2;++q)
                GLDS(Az + (size_t)(i0 + wv*32 + q*16 + (lane>>2))*lda + k0 + (lane&3)*8,
                     As + (wv*32 + q*16)*32);
        }
        // ---- stage B tile [128 cols][32 k] bf16 into Bs
        if constexpr (BBITS) {
            const int row = t & 127, half = t >> 7;
            unsigned v = Bz[(size_t)(j0+row)*ldb + (k0>>4) + half];
            u16* p = Bs + row*32 + half*16;
            uint4 w0, w1;
            w0.x=PK(0);  w0.y=PK(2);  w0.z=PK(4);  w0.w=PK(6);
            w1.x=PK(8);  w1.y=PK(10); w1.z=PK(12); w1.w=PK(14);
            #undef PK
            *(uint4*)p = w0; *(uint4*)(p+8) = w1;
        } else {
            #pragma unroll
            for (int q=0;q<2;++q)
                GLDS(Bz + (size_t)(j0 + wv*32 + q*16 + (lane>>2))*ldb + k0 + (lane&3)*8,
                     Bs + (wv*32 + q*16)*32);
        }
        if constexpr (SPLIT) {
            #pragma unroll
            for (int q=0;q<2;++q) {
                GLDS(A2z + (size_t)(i0 + wv*32 + q*16 + (lane>>2))*lda + k0 + (lane&3)*8,
                     As2 + (wv*32 + q*16)*32);
                GLDS(B2z + (size_t)(j0 + wv*32 + q*16 + (lane>>2))*ldb + k0 + (lane&3)*8,
                     Bs2 + (wv*32 + q*16)*32);
            }
        }
        __syncthreads();

        // ---- fragments: A row=lane&15, k=(lane>>4)*8+i ; B col=lane&15, same k
        bf16x8 fa[4], fb[4];
        #pragma unroll
        for (int m=0;m<4;++m) fa[m] = *(const bf16x8*)&As[(wr + m*16 + (lane&15))*32 + (lane>>4)*8];
        #pragma unroll
        for (int n=0;n<4;++n) fb[n] = *(const bf16x8*)&Bs[(wc + n*16 + (lane&15))*32 + (lane>>4)*8];
        if constexpr (SPLIT) {
            bf16x8 fa2[4], fb2[4];
            #pragma unroll
            for (int m=0;m<4;++m) fa2[m] = *(const bf16x8*)&As2[(wr + m*16 + (lane&15))*32 + (lane>>4)*8];
            #pragma unroll
            for (int n=0;n<4;++n) fb2[n] = *(const bf16x8*)&Bs2[(wc + n*16 + (lane&15))*32 + (lane>>4)*8];
            #pragma unroll
            for (int m=0;m<4;++m)
                #pragma unroll
                for (int n=0;n<4;++n) {
                    acc[m][n] = __builtin_amdgcn_mfma_f32_16x16x32_bf16(fa[m],  fb[n],  acc[m][n], 0,0,0);
                    acc[m][n] = __builtin_amdgcn_mfma_f32_16x16x32_bf16(fa[m],  fb2[n], acc[m][n], 0,0,0);
                    acc[m][n] = __builtin_amdgcn_mfma_f32_16x16x32_bf16(fa2[m], fb[n],  acc[m][n], 0,0,0);
                }
        } else {
            #pragma unroll
            for (int m=0;m<4;++m)
                #pragma unroll
                for (int n=0;n<4;++n)
                    acc[m][n] = __builtin_amdgcn_mfma_f32_16x16x32_bf16(fa[m], fb[n], acc[m][n], 0,0,0);
        }
        __syncthreads();
    }

    // ---- epilogue.  C/D frag: col=lane&15, row=(lane>>4)*4 + j  [m89-verified]
    const int cl = lane & 15, rg = lane >> 4;
    if constexpr (EPI == 1) {
        u16* hgb  = (u16*)C  + (size_t)z*sC;
        u16* hgtb = (u16*)C2 + (size_t)z*sC2;
        const float* v1z = v1 + (size_t)z*sv1;
        const float* v2z = v2 + (size_t)z*sv2;
        #pragma unroll
        for (int m=0;m<4;++m) {
            #pragma unroll
            for (int n=0;n<4;++n) {
                const int rb = i0 + wr + m*16;
                const int cb = j0 + wc + n*16;
                const float n2c = v2z[cb + cl];
                unsigned long long b0,b1,b2,b3;
                { float s = v1z[rb+rg*4+0] + n2c - 2.f*acc[m][n][0]; b0 = __ballot(s < 529.f); }
                { float s = v1z[rb+rg*4+1] + n2c - 2.f*acc[m][n][1]; b1 = __ballot(s < 529.f); }
                { float s = v1z[rb+rg*4+2] + n2c - 2.f*acc[m][n][2]; b2 = __ballot(s < 529.f); }
                { float s = v1z[rb+rg*4+3] + n2c - 2.f*acc[m][n][3]; b3 = __ballot(s < 529.f); }
                // hg[n][m] bits: row = rb + rg*4 + cl (cl<4), 16-col chunk
                unsigned long long bsel = (cl&2) ? ((cl&1)? b3 : b2) : ((cl&1)? b1 : b0);
                if (cl < 4)
                    hgb[(size_t)(rb + rg*4 + cl)*ldc + (cb>>4)] = (u16)((bsel >> (rg*16)) & 0xFFFFull);
                // hgT[m][n] bits: lanes 0..15 (rg==0), col c=cl gathers 16 rows
                if (rg == 0) {
                    unsigned tb = 0;
                    #pragma unroll
                    for (int k=0;k<16;++k) {
                        unsigned long long bb = (k&2) ? ((k&1)? b3:b2) : ((k&1)? b1:b0);
                        tb |= (unsigned)((bb >> ((k>>2)*16 + cl)) & 1ull) << k;
                    }
                    hgtb[(size_t)(cb + cl)*ldc + (rb>>4)] = (u16)tb;
                }
            }
        }
    } else {
        float* Cf  = (float*)C  + (size_t)z*sC;
        u16*   Cb  = (u16*)C    + (size_t)z*sC;
        u16*   C2b = (u16*)C2   + (size_t)z*sC2;
        const float* Rf = (const float*)resid + (size_t)z*sR;
        const u16*   Rb = (const u16*)resid   + (size_t)z*sR;
        const float* v1z = v1 ? v1 + (size_t)z*sv1 : nullptr;
        const float* v2z = v2 ? v2 + (size_t)z*sv2 : nullptr;
        #pragma unroll
        for (int m=0;m<4;++m) {
            #pragma unroll
            for (int n=0;n<4;++n) {
                const int cc = j0 + wc + n*16 + cl;
                #pragma unroll
                for (int j=0;j<4;++j) {
                    const int r = i0 + wr + m*16 + rg*4 + j;
                    const float v = acc[m][n][j];
                    if constexpr (EPI == 0) {
                        Cb[(size_t)r*ldc + cc] = f2bf(v + bias[r]);
                    } else if constexpr (EPI == 2) {
                        float d = v2z[cc]; float nm = d > 0.f ? 1.f/d : 0.f;
                        Cb[(size_t)r*ldc + cc] = f2bf(v*nm + bf2f(Rb[(size_t)r*ldc + cc]));
                    } else if constexpr (EPI == 3) {
                        float d = v1z[r]; float nm = d > 0.f ? 1.f/d : 0.f;
                        float o = v*nm + Rf[(size_t)r*ldc + cc];
                        Cf [(size_t)r*ldc + cc] = o;
                        C2b[(size_t)r*ldc + cc] = f2bf(o);
                    } else if constexpr (EPI == 4) {
                        float o = v + bias[cc];
                        Cb[(size_t)r*ldc + cc] = f2bf(o > 0.f ? o : 0.f);
                    } else {
                        Cf[(size_t)r*ldc + cc] = v + bias[cc] + Rf[(size_t)r*ldc + cc];
                    }
                }
            }
        }
    }
}

// ---- hi/lo split conversion: hi=bf16(x), lo=bf16(x-hi) --------------------
__global__ __launch_bounds__(256)
void cvth_k(const float* __restrict__ x, u16* __restrict__ hi, u16* __restrict__ lo)
{
    size_t i = ((size_t)blockIdx.x*256 + threadIdx.x)*4;
    float4 v = ld4(x + i);
    ushort4 h, l;
    h.x = f2bf(v.x); l.x = f2bf(v.x - bf2f(h.x));
    h.y = f2bf(v.y); l.y = f2bf(v.y - bf2f(h.y));
    h.z = f2bf(v.z); l.z = f2bf(v.z - bf2f(h.z));
    h.w = f2bf(v.w); l.w = f2bf(v.w - bf2f(h.w));
    *(ushort4*)(hi+i) = h; *(ushort4*)(lo+i) = l;
}

// ---- weight bf16 conversion -----------------------------------------------
__global__ __launch_bounds__(256)
void cvtw_k(const float* __restrict__ wfc, const float* __restrict__ w1,
            const float* __restrict__ w2, u16* __restrict__ owfc,
            u16* __restrict__ ow1, u16* __restrict__ ow2)
{
    int i = blockIdx.x*256 + threadIdx.x;
    if (i < 65536)  owfc[i] = f2bf(wfc[i]);
    if (i < 262144) { ow1[i] = f2bf(w1[i]); ow2[i] = f2bf(w2[i]); }
}

// ---- disc [b][n][d] f32 -> discT [b][d][n] bf16 ---------------------------
__global__ __launch_bounds__(256)
void tr_k(const float* __restrict__ src, u16* __restrict__ dst)
{
    __shared__ float tl[64][65];
    const int b = blockIdx.z, n0 = blockIdx.x*64, d0 = blockIdx.y*64;
    const float* s = src + (size_t)b*1048576;
    u16* o = dst + (size_t)b*1048576;
    const int tx = threadIdx.x & 15, ty = threadIdx.x >> 4;
    #pragma unroll
    for (int it=0; it<4; ++it) {
        int r = ty + it*16;
        float4 v = ld4(s + (size_t)(n0+r)*256 + d0 + tx*4);
        tl[r][tx*4+0]=v.x; tl[r][tx*4+1]=v.y; tl[r][tx*4+2]=v.z; tl[r][tx*4+3]=v.w;
    }
    __syncthreads();
    #pragma unroll
    for (int it=0; it<4; ++it) {
        int d = ty + it*16;
        ushort4 w;
        w.x = f2bf(tl[tx*4+0][d]); w.y = f2bf(tl[tx*4+1][d]);
        w.z = f2bf(tl[tx*4+2][d]); w.w = f2bf(tl[tx*4+3][d]);
        *(ushort4*)(o + (size_t)(d0+d)*4096 + n0 + tx*4) = w;
    }
}

// ---- row squared-norms ----------------------------------------------------
__global__ __launch_bounds__(256)
void rownorm_k(const float* __restrict__ ind, const float* __restrict__ disc,
               float* __restrict__ n1, float* __restrict__ n2, int rows)
{
    int wid = threadIdx.x >> 6, lane = threadIdx.x & 63;
    int r = blockIdx.x*4 + wid;
    const float* src; float* dst; int rr;
    if (r < rows) { src = ind;  dst = n1; rr = r; }
    else          { src = disc; dst = n2; rr = r - rows; }
    float4 v = ld4(src + (size_t)rr*256 + lane*4);
    float s = v.x*v.x + v.y*v.y + v.z*v.z + v.w*v.w;
    #pragma unroll
    for (int o=32;o;o>>=1) s += __shfl_down(s, o);
    if (lane == 0) dst[rr] = s;
}

// ---- degree = popcount of a bit-row (256 u16 chunks = 128 dwords) ---------
__global__ __launch_bounds__(256)
void popc_k(const u16* __restrict__ bits, float* __restrict__ deg)
{
    int wv = threadIdx.x >> 6, lane = threadIdx.x & 63;
    size_t row = (size_t)blockIdx.x*4 + wv;
    const unsigned* p = (const unsigned*)(bits + row*256);
    int s = __popc(p[lane]) + __popc(p[lane+64]);
    #pragma unroll
    for (int o=32;o;o>>=1) s += __shfl_down(s, o);
    if (lane == 0) deg[row] = (float)s;
}

// ---- LayerNorm over D=256 -------------------------------------------------
__global__ __launch_bounds__(256)
void ln_k(const float* __restrict__ q, const float* __restrict__ g,
          const float* __restrict__ bta, float* __restrict__ out)
{
    size_t row = blockIdx.x;
    int t = threadIdx.x;
    float x = q[row*256 + t];
    float s1 = x, s2 = x*x;
    int lane = t & 63, wid = t >> 6;
    #pragma unroll
    for (int o=32;o;o>>=1) { s1 += __shfl_down(s1,o); s2 += __shfl_down(s2,o); }
    __shared__ float a1[4], a2[4];
    if (lane == 0) { a1[wid]=s1; a2[wid]=s2; }
    __syncthreads();
    s1 = a1[0]+a1[1]+a1[2]+a1[3];
    s2 = a2[0]+a2[1]+a2[2]+a2[3];
    float mu  = s1 * (1.f/256.f);
    float var = s2 * (1.f/256.f) - mu*mu;
    float r = rsqrtf(var + 1e-5f);
    out[row*256 + t] = (x - mu) * r * g[t] + bta[t];
}

extern "C" void kernel_launch(void* const* d_in, const int* in_sizes, int n_in,
                              void* d_out, int out_size, void* d_ws, size_t ws_size,
                              hipStream_t stream)
{
    const float* disc = (const float*)d_in[0];
    const float* ind  = (const float*)d_in[1];
    const float* W_fc = (const float*)d_in[2];
    const float* b_fc = (const float*)d_in[3];
    const float* W1   = (const float*)d_in[4];
    const float* b1   = (const float*)d_in[5];
    const float* W2   = (const float*)d_in[6];
    const float* b2   = (const float*)d_in[7];
    const float* ln_g = (const float*)d_in[8];
    const float* ln_b = (const float*)d_in[9];
    float* out = (float*)d_out;

    char* ws = (char*)d_ws;
    // workspace layout (peak ~194MB, under the 235MB proven in round 3)
    u16* hgb   = (u16*)(ws + 0);           // hg  bits [b][n][256ch]   16.78MB
    u16* hgtb  = (u16*)(ws + 16777216);    // hgT bits [b][m][256ch]   16.78MB
    u16* ETb   = (u16*)(ws + 33554432);    // E^T bf16 [b][256][4096]  16.78MB
    u16* ih    = (u16*)(ws + 50331648);    // ind hi                   16.78MB
    u16* il    = (u16*)(ws + 67108864);    // ind lo                   16.78MB
    u16* dh    = (u16*)(ws + 83886080);    // disc hi                  16.78MB
    u16* dl    = (u16*)(ws + 100663296);   // disc lo                  16.78MB
    u16* discT = (u16*)(ws + 117440512);   // disc^T bf16              16.78MB
    u16* XTb   = (u16*)(ws + 134217728);   // X^T bf16 [b][256][4096]  16.78MB
    float* enhF= (float*)(ws + 150994944); // enh f32 [BN][256]        33.55MB
    u16* enhB  = (u16*)(ws + 184549376);   // enh bf16                 16.78MB
    u16* wfcb  = (u16*)(ws + 201326592);
    u16* w1b   = (u16*)(ws + 201457664);
    u16* w2b   = (u16*)(ws + 201981952);
    float* n1  = (float*)(ws + 202506240);
    float* n2  = (float*)(ws + 202637312);
    float* dN  = (float*)(ws + 202768384);
    float* dE  = (float*)(ws + 202899456);
    u16* hB    = (u16*)(ws + 83886080);    // h bf16 [BN][1024] aliases dh..XTb (dead)
    float* qF  = (float*)(ws + 50331648);  // q f32 aliases ih+il (dead)

    const int BN = 32768;
    const long long S = 1048576;  // 4096*256 elements / 256*4096 / bit-chunks per batch

    cvth_k<<<8192, 256, 0, stream>>>(ind,  ih, il);
    cvth_k<<<8192, 256, 0, stream>>>(disc, dh, dl);
    cvtw_k<<<1024, 256, 0, stream>>>(W_fc, W1, W2, wfcb, w1b, w2b);
    rownorm_k<<<16384, 256, 0, stream>>>(ind, disc, n1, n2, BN);
    tr_k<<<dim3(64,4,8), 256, 0, stream>>>(disc, discT);

    // gram (split): hg[b,n,m] = (n1[n]+n2[m]-2*ind.disc < 529), bit-packed both ways
    mg<1,true,false,false><<<dim3(32,32,8), 256, 0, stream>>>(
        ih, il, dh, dl, hgb, hgtb, 256, 256, 256, 256,
        S, S, S, S, nullptr, n1, 4096, n2, 4096, nullptr, 0);

    popc_k<<<8192, 256, 0, stream>>>(hgb,  dN);   // degN[n] = sum_e hg[n][e]
    popc_k<<<8192, 256, 0, stream>>>(hgtb, dE);   // degE[e] = sum_n hg[n][e]

    // XT[b][c][n] = sum_d W_fc[c,d]*ind[b,n,d] + b_fc[c]
    mg<0,false,false,false><<<dim3(2,32,8), 256, 0, stream>>>(
        wfcb, nullptr, ih, nullptr, XTb, nullptr, 256, 256, 256, 4096,
        0, S, S, 0, b_fc, nullptr, 0, nullptr, 0, nullptr, 0);

    // ET[b][c][e] = (sum_n XT[c][n]*hgT[e][n]) / degE[e] + discT[c][e]
    mg<2,false,false,true><<<dim3(2,32,8), 256, 0, stream>>>(
        XTb, nullptr, hgtb, nullptr, ETb, nullptr, 4096, 4096, 256, 4096,
        S, S, S, 0, nullptr, nullptr, 0, dE, 4096, discT, S);

    // enh[b][n][c] = (sum_e hg[n][e]*ET[c][e]) / degN[n] + ind[b,n,c]  (f32 + bf16)
    mg<3,false,true,false><<<dim3(32,2,8), 256, 0, stream>>>(
        hgb, nullptr, ETb, nullptr, enhF, enhB, 4096, 256, 4096, 256,
        S, S, S, S, nullptr, dN, 4096, nullptr, 0, ind, S);

    // h = relu(enh @ W1^T + b1)
    mg<4,false,false,false><<<dim3(256,8,1), 256, 0, stream>>>(
        enhB, nullptr, w1b, nullptr, hB, nullptr, 256, 256, 256, 1024,
        0, 0, 0, 0, b1, nullptr, 0, nullptr, 0, nullptr, 0);

    // q = h @ W2^T + b2 + enh   (f32)
    mg<5,false,false,false><<<dim3(256,2,1), 256, 0, stream>>>(
        hB, nullptr, w2b, nullptr, qF, nullptr, 1024, 1024, 1024, 256,
        0, 0, 0, 0, b2, nullptr, 0, nullptr, 0, enhF, 0);

    ln_k<<<BN, 256, 0, stream>>>(qF, ln_g, ln_b, out);
}

// Round 7
// 781.365 us; speedup vs baseline: 3.8366x; 1.1899x over previous
//
#include <hip/hip_runtime.h>
#include <stdint.h>

// B=8, N=4096, D=256, F=1024.  MFMA 16x16x32 bf16, 128x128 tiles, 4 waves.
// hg bit-packed in both orientations (L3-resident aggregations).
// Gram: hi/lo split-bf16 (3 MFMA) for f32-level threshold accuracy.
// R5: LDS XOR-swizzle (chunk ^= (row>>1)&3) on ALL staging (GLDS source-permute
//     per rule #21, ds_write addr for bit-unpack) + fragment reads; fused prep.

typedef unsigned short u16;
typedef __attribute__((ext_vector_type(8))) short bf16x8;
typedef __attribute__((ext_vector_type(4))) float f32x4;

#define GLDS(g, l) __builtin_amdgcn_global_load_lds((const __attribute__((address_space(1))) void*)(g), (__attribute__((address_space(3))) void*)(l), 16, 0, 0)

__device__ __forceinline__ float4 ld4(const float* p){ return *reinterpret_cast<const float4*>(p); }
__device__ __forceinline__ u16 f2bf(float f){
    union{float f;unsigned u;}x{f};
    unsigned r=(x.u+0x7FFFu+((x.u>>16)&1u))>>16; return (u16)r;
}
__device__ __forceinline__ float bf2f(u16 s){
    union{unsigned u;float f;}x{(unsigned)s<<16}; return x.f;
}
__device__ __forceinline__ unsigned pk2(unsigned v, int i){
    return (((v>>i)&1u)*0x3F80u) | (((v>>(i+1))&1u)*0x3F800000u);
}

// ---------------------------------------------------------------------------
// Unified MFMA GEMM.  C[i,j] = sum_k A[i,k]*B[k,j].
// LDS tile: [128 rows][4 chunks of 8 u16]; physical chunk = logical ^ ((row>>1)&3).
// ---------------------------------------------------------------------------
template<int EPI, bool SPLIT, bool ABITS, bool BBITS>
__global__ __launch_bounds__(256)
void mg(const u16* __restrict__ A, const u16* __restrict__ A2,
        const u16* __restrict__ Bt, const u16* __restrict__ B2,
        void* __restrict__ C, void* __restrict__ C2,
        int K, int lda, int ldb, int ldc,
        long long sA, long long sB, long long sC, long long sC2,
        const float* __restrict__ bias,
        const float* __restrict__ v1, long long sv1,
        const float* __restrict__ v2, long long sv2,
        const void* __restrict__ resid, long long sR)
{
    __shared__ u16 As[4096], Bs[4096];
    __shared__ u16 As2[SPLIT ? 4096 : 8], Bs2[SPLIT ? 4096 : 8];
    const int t = threadIdx.x, lane = t & 63, wv = t >> 6;
    const int i0 = blockIdx.x*128, j0 = blockIdx.y*128, z = blockIdx.z;
    const int wr = (wv>>1)*64, wc = (wv&1)*64;

    const u16* Az  = A  + (size_t)z*sA;
    const u16* Bz  = Bt + (size_t)z*sB;
    const u16* A2z = SPLIT ? A2 + (size_t)z*sA : nullptr;
    const u16* B2z = SPLIT ? B2 + (size_t)z*sB : nullptr;

    // staging geometry (GLDS path): lane -> LDS row lr, source chunk swizzled
    const int glr = lane >> 2;                       // row-within-16 per GLDS call
    const int gsc = (lane & 3) ^ ((glr >> 1) & 3);   // swizzled source chunk
    // fragment-read geometry: per-lane constant chunk offset
    const int frow = lane & 15;
    const int fcho = ((lane >> 4) ^ ((frow >> 1) & 3)) * 8;

    f32x4 zero4 = {0.f,0.f,0.f,0.f};
    f32x4 acc[4][4];
    #pragma unroll
    for (int m=0;m<4;++m)
        #pragma unroll
        for (int n=0;n<4;++n) acc[m][n] = zero4;

    for (int k0 = 0; k0 < K; k0 += 32) {
        if constexpr (ABITS) {
            const int row = t & 127, half = t >> 7, sw = (row>>1)&3;
            unsigned v = Az[(size_t)(i0+row)*lda + (k0>>4) + half];
            u16* base = As + row*32;
            uint4 w0, w1;
            w0.x=pk2(v,0);  w0.y=pk2(v,2);  w0.z=pk2(v,4);  w0.w=pk2(v,6);
            w1.x=pk2(v,8);  w1.y=pk2(v,10); w1.z=pk2(v,12); w1.w=pk2(v,14);
            *(uint4*)(base + ((2*half  )^sw)*8) = w0;
            *(uint4*)(base + ((2*half+1)^sw)*8) = w1;
        } else {
            #pragma unroll
            for (int q=0;q<2;++q) {
                const int lr = wv*32 + q*16 + glr;
                GLDS(Az + (size_t)(i0+lr)*lda + k0 + gsc*8, As + (wv*32 + q*16)*32);
            }
        }
        if constexpr (BBITS) {
            const int row = t & 127, half = t >> 7, sw = (row>>1)&3;
            unsigned v = Bz[(size_t)(j0+row)*ldb + (k0>>4) + half];
            u16* base = Bs + row*32;
            uint4 w0, w1;
            w0.x=pk2(v,0);  w0.y=pk2(v,2);  w0.z=pk2(v,4);  w0.w=pk2(v,6);
            w1.x=pk2(v,8);  w1.y=pk2(v,10); w1.z=pk2(v,12); w1.w=pk2(v,14);
            *(uint4*)(base + ((2*half  )^sw)*8) = w0;
            *(uint4*)(base + ((2*half+1)^sw)*8) = w1;
        } else {
            #pragma unroll
            for (int q=0;q<2;++q) {
                const int lr = wv*32 + q*16 + glr;
                GLDS(Bz + (size_t)(j0+lr)*ldb + k0 + gsc*8, Bs + (wv*32 + q*16)*32);
            }
        }
        if constexpr (SPLIT) {
            #pragma unroll
            for (int q=0;q<2;++q) {
                const int lr = wv*32 + q*16 + glr;
                GLDS(A2z + (size_t)(i0+lr)*lda + k0 + gsc*8, As2 + (wv*32 + q*16)*32);
                GLDS(B2z + (size_t)(j0+lr)*ldb + k0 + gsc*8, Bs2 + (wv*32 + q*16)*32);
            }
        }
        __syncthreads();

        bf16x8 fa[4], fb[4];
        #pragma unroll
        for (int m=0;m<4;++m) fa[m] = *(const bf16x8*)&As[(wr + m*16 + frow)*32 + fcho];
        #pragma unroll
        for (int n=0;n<4;++n) fb[n] = *(const bf16x8*)&Bs[(wc + n*16 + frow)*32 + fcho];
        if constexpr (SPLIT) {
            bf16x8 fa2[4], fb2[4];
            #pragma unroll
            for (int m=0;m<4;++m) fa2[m] = *(const bf16x8*)&As2[(wr + m*16 + frow)*32 + fcho];
            #pragma unroll
            for (int n=0;n<4;++n) fb2[n] = *(const bf16x8*)&Bs2[(wc + n*16 + frow)*32 + fcho];
            #pragma unroll
            for (int m=0;m<4;++m)
                #pragma unroll
                for (int n=0;n<4;++n) {
                    acc[m][n] = __builtin_amdgcn_mfma_f32_16x16x32_bf16(fa[m],  fb[n],  acc[m][n], 0,0,0);
                    acc[m][n] = __builtin_amdgcn_mfma_f32_16x16x32_bf16(fa[m],  fb2[n], acc[m][n], 0,0,0);
                    acc[m][n] = __builtin_amdgcn_mfma_f32_16x16x32_bf16(fa2[m], fb[n],  acc[m][n], 0,0,0);
                }
        } else {
            #pragma unroll
            for (int m=0;m<4;++m)
                #pragma unroll
                for (int n=0;n<4;++n)
                    acc[m][n] = __builtin_amdgcn_mfma_f32_16x16x32_bf16(fa[m], fb[n], acc[m][n], 0,0,0);
        }
        __syncthreads();
    }

    // ---- epilogue.  C/D frag: col=lane&15, row=(lane>>4)*4 + j
    const int cl = lane & 15, rg = lane >> 4;
    if constexpr (EPI == 1) {
        u16* hgb  = (u16*)C  + (size_t)z*sC;
        u16* hgtb = (u16*)C2 + (size_t)z*sC2;
        const float* v1z = v1 + (size_t)z*sv1;
        const float* v2z = v2 + (size_t)z*sv2;
        #pragma unroll
        for (int m=0;m<4;++m) {
            #pragma unroll
            for (int n=0;n<4;++n) {
                const int rb = i0 + wr + m*16;
                const int cb = j0 + wc + n*16;
                const float n2c = v2z[cb + cl];
                unsigned long long b0,b1,b2,b3;
                { float s = v1z[rb+rg*4+0] + n2c - 2.f*acc[m][n][0]; b0 = __ballot(s < 529.f); }
                { float s = v1z[rb+rg*4+1] + n2c - 2.f*acc[m][n][1]; b1 = __ballot(s < 529.f); }
                { float s = v1z[rb+rg*4+2] + n2c - 2.f*acc[m][n][2]; b2 = __ballot(s < 529.f); }
                { float s = v1z[rb+rg*4+3] + n2c - 2.f*acc[m][n][3]; b3 = __ballot(s < 529.f); }
                unsigned long long bsel = (cl&2) ? ((cl&1)? b3 : b2) : ((cl&1)? b1 : b0);
                if (cl < 4)
                    hgb[(size_t)(rb + rg*4 + cl)*ldc + (cb>>4)] = (u16)((bsel >> (rg*16)) & 0xFFFFull);
                if (rg == 0) {
                    unsigned tb = 0;
                    #pragma unroll
                    for (int k=0;k<16;++k) {
                        unsigned long long bb = (k&2) ? ((k&1)? b3:b2) : ((k&1)? b1:b0);
                        tb |= (unsigned)((bb >> ((k>>2)*16 + cl)) & 1ull) << k;
                    }
                    hgtb[(size_t)(cb + cl)*ldc + (rb>>4)] = (u16)tb;
                }
            }
        }
    } else {
        float* Cf  = (float*)C  + (size_t)z*sC;
        u16*   Cb  = (u16*)C    + (size_t)z*sC;
        u16*   C2b = (u16*)C2   + (size_t)z*sC2;
        const float* Rf = (const float*)resid + (size_t)z*sR;
        const u16*   Rb = (const u16*)resid   + (size_t)z*sR;
        const float* v1z = v1 ? v1 + (size_t)z*sv1 : nullptr;
        const float* v2z = v2 ? v2 + (size_t)z*sv2 : nullptr;
        #pragma unroll
        for (int m=0;m<4;++m) {
            #pragma unroll
            for (int n=0;n<4;++n) {
                const int cc = j0 + wc + n*16 + cl;
                #pragma unroll
                for (int j=0;j<4;++j) {
                    const int r = i0 + wr + m*16 + rg*4 + j;
                    const float v = acc[m][n][j];
                    if constexpr (EPI == 0) {
                        Cb[(size_t)r*ldc + cc] = f2bf(v + bias[r]);
                    } else if constexpr (EPI == 2) {
                        float d = v2z[cc]; float nm = d > 0.f ? 1.f/d : 0.f;
                        Cb[(size_t)r*ldc + cc] = f2bf(v*nm + bf2f(Rb[(size_t)r*ldc + cc]));
                    } else if constexpr (EPI == 3) {
                        float d = v1z[r]; float nm = d > 0.f ? 1.f/d : 0.f;
                        float o = v*nm + Rf[(size_t)r*ldc + cc];
                        Cf [(size_t)r*ldc + cc] = o;
                        C2b[(size_t)r*ldc + cc] = f2bf(o);
                    } else if constexpr (EPI == 4) {
                        float o = v + bias[cc];
                        Cb[(size_t)r*ldc + cc] = f2bf(o > 0.f ? o : 0.f);
                    } else {
                        Cf[(size_t)r*ldc + cc] = v + bias[cc] + Rf[(size_t)r*ldc + cc];
                    }
                }
            }
        }
    }
}

// ---- fused prep: hi/lo split of ind & disc + row squared-norms ------------
__global__ __launch_bounds__(256)
void prep_k(const float* __restrict__ ind, const float* __restrict__ disc,
            u16* __restrict__ ih, u16* __restrict__ il,
            u16* __restrict__ dh, u16* __restrict__ dl,
            float* __restrict__ n1, float* __restrict__ n2, int rows)
{
    int wid = threadIdx.x >> 6, lane = threadIdx.x & 63;
    int r = blockIdx.x*4 + wid;
    const float* src; u16 *hi, *lo; float* dst; int rr;
    if (r < rows) { src = ind;  hi = ih; lo = il; dst = n1; rr = r; }
    else          { src = disc; hi = dh; lo = dl; dst = n2; rr = r - rows; }
    size_t off = (size_t)rr*256 + lane*4;
    float4 v = ld4(src + off);
    ushort4 h, l;
    h.x = f2bf(v.x); l.x = f2bf(v.x - bf2f(h.x));
    h.y = f2bf(v.y); l.y = f2bf(v.y - bf2f(h.y));
    h.z = f2bf(v.z); l.z = f2bf(v.z - bf2f(h.z));
    h.w = f2bf(v.w); l.w = f2bf(v.w - bf2f(h.w));
    *(ushort4*)(hi+off) = h; *(ushort4*)(lo+off) = l;
    float s = v.x*v.x + v.y*v.y + v.z*v.z + v.w*v.w;
    #pragma unroll
    for (int o=32;o;o>>=1) s += __shfl_down(s, o);
    if (lane == 0) dst[rr] = s;
}

// ---- weight bf16 conversion -----------------------------------------------
__global__ __launch_bounds__(256)
void cvtw_k(const float* __restrict__ wfc, const float* __restrict__ w1,
            const float* __restrict__ w2, u16* __restrict__ owfc,
            u16* __restrict__ ow1, u16* __restrict__ ow2)
{
    int i = blockIdx.x*256 + threadIdx.x;
    if (i < 65536)  owfc[i] = f2bf(wfc[i]);
    if (i < 262144) { ow1[i] = f2bf(w1[i]); ow2[i] = f2bf(w2[i]); }
}

// ---- disc [b][n][d] f32 -> discT [b][d][n] bf16 ---------------------------
__global__ __launch_bounds__(256)
void tr_k(const float* __restrict__ src, u16* __restrict__ dst)
{
    __shared__ float tl[64][65];
    const int b = blockIdx.z, n0 = blockIdx.x*64, d0 = blockIdx.y*64;
    const float* s = src + (size_t)b*1048576;
    u16* o = dst + (size_t)b*1048576;
    const int tx = threadIdx.x & 15, ty = threadIdx.x >> 4;
    #pragma unroll
    for (int it=0; it<4; ++it) {
        int r = ty + it*16;
        float4 v = ld4(s + (size_t)(n0+r)*256 + d0 + tx*4);
        tl[r][tx*4+0]=v.x; tl[r][tx*4+1]=v.y; tl[r][tx*4+2]=v.z; tl[r][tx*4+3]=v.w;
    }
    __syncthreads();
    #pragma unroll
    for (int it=0; it<4; ++it) {
        int d = ty + it*16;
        ushort4 w;
        w.x = f2bf(tl[tx*4+0][d]); w.y = f2bf(tl[tx*4+1][d]);
        w.z = f2bf(tl[tx*4+2][d]); w.w = f2bf(tl[tx*4+3][d]);
        *(ushort4*)(o + (size_t)(d0+d)*4096 + n0 + tx*4) = w;
    }
}

// ---- degree = popcount of a bit-row ---------------------------------------
__global__ __launch_bounds__(256)
void popc_k(const u16* __restrict__ bits, float* __restrict__ deg)
{
    int wv = threadIdx.x >> 6, lane = threadIdx.x & 63;
    size_t row = (size_t)blockIdx.x*4 + wv;
    const unsigned* p = (const unsigned*)(bits + row*256);
    int s = __popc(p[lane]) + __popc(p[lane+64]);
    #pragma unroll
    for (int o=32;o;o>>=1) s += __shfl_down(s, o);
    if (lane == 0) deg[row] = (float)s;
}

// ---- LayerNorm over D=256 -------------------------------------------------
__global__ __launch_bounds__(256)
void ln_k(const float* __restrict__ q, const float* __restrict__ g,
          const float* __restrict__ bta, float* __restrict__ out)
{
    size_t row = blockIdx.x;
    int t = threadIdx.x;
    float x = q[row*256 + t];
    float s1 = x, s2 = x*x;
    int lane = t & 63, wid = t >> 6;
    #pragma unroll
    for (int o=32;o;o>>=1) { s1 += __shfl_down(s1,o); s2 += __shfl_down(s2,o); }
    __shared__ float a1[4], a2[4];
    if (lane == 0) { a1[wid]=s1; a2[wid]=s2; }
    __syncthreads();
    s1 = a1[0]+a1[1]+a1[2]+a1[3];
    s2 = a2[0]+a2[1]+a2[2]+a2[3];
    float mu  = s1 * (1.f/256.f);
    float var = s2 * (1.f/256.f) - mu*mu;
    float r = rsqrtf(var + 1e-5f);
    out[row*256 + t] = (x - mu) * r * g[t] + bta[t];
}

extern "C" void kernel_launch(void* const* d_in, const int* in_sizes, int n_in,
                              void* d_out, int out_size, void* d_ws, size_t ws_size,
                              hipStream_t stream)
{
    const float* disc = (const float*)d_in[0];
    const float* ind  = (const float*)d_in[1];
    const float* W_fc = (const float*)d_in[2];
    const float* b_fc = (const float*)d_in[3];
    const float* W1   = (const float*)d_in[4];
    const float* b1   = (const float*)d_in[5];
    const float* W2   = (const float*)d_in[6];
    const float* b2   = (const float*)d_in[7];
    const float* ln_g = (const float*)d_in[8];
    const float* ln_b = (const float*)d_in[9];
    float* out = (float*)d_out;

    char* ws = (char*)d_ws;
    u16* hgb   = (u16*)(ws + 0);           // hg  bits [b][n][256ch]   16.78MB
    u16* hgtb  = (u16*)(ws + 16777216);    // hgT bits [b][m][256ch]   16.78MB
    u16* ETb   = (u16*)(ws + 33554432);    // E^T bf16 [b][256][4096]  16.78MB
    u16* ih    = (u16*)(ws + 50331648);
    u16* il    = (u16*)(ws + 67108864);
    u16* dh    = (u16*)(ws + 83886080);
    u16* dl    = (u16*)(ws + 100663296);
    u16* discT = (u16*)(ws + 117440512);
    u16* XTb   = (u16*)(ws + 134217728);
    float* enhF= (float*)(ws + 150994944); // enh f32 [BN][256]        33.55MB
    u16* enhB  = (u16*)(ws + 184549376);
    u16* wfcb  = (u16*)(ws + 201326592);
    u16* w1b   = (u16*)(ws + 201457664);
    u16* w2b   = (u16*)(ws + 201981952);
    float* n1  = (float*)(ws + 202506240);
    float* n2  = (float*)(ws + 202637312);
    float* dN  = (float*)(ws + 202768384);
    float* dE  = (float*)(ws + 202899456);
    u16* hB    = (u16*)(ws + 83886080);    // h bf16 aliases dh..XTb (dead)
    float* qF  = (float*)(ws + 50331648);  // q f32 aliases ih+il (dead)

    const int BN = 32768;
    const long long S = 1048576;

    prep_k<<<16384, 256, 0, stream>>>(ind, disc, ih, il, dh, dl, n1, n2, BN);
    cvtw_k<<<1024, 256, 0, stream>>>(W_fc, W1, W2, wfcb, w1b, w2b);
    tr_k<<<dim3(64,4,8), 256, 0, stream>>>(disc, discT);

    // gram (split): hg = bit-packed both orientations
    mg<1,true,false,false><<<dim3(32,32,8), 256, 0, stream>>>(
        ih, il, dh, dl, hgb, hgtb, 256, 256, 256, 256,
        S, S, S, S, nullptr, n1, 4096, n2, 4096, nullptr, 0);

    popc_k<<<8192, 256, 0, stream>>>(hgb,  dN);
    popc_k<<<8192, 256, 0, stream>>>(hgtb, dE);

    // XT[b][c][n] = sum_d W_fc[c,d]*ind[b,n,d] + b_fc[c]
    mg<0,false,false,false><<<dim3(2,32,8), 256, 0, stream>>>(
        wfcb, nullptr, ih, nullptr, XTb, nullptr, 256, 256, 256, 4096,
        0, S, S, 0, b_fc, nullptr, 0, nullptr, 0, nullptr, 0);

    // ET[b][c][e] = (sum_n XT[c][n]*hgT[e][n]) / degE[e] + discT[c][e]
    mg<2,false,false,true><<<dim3(2,32,8), 256, 0, stream>>>(
        XTb, nullptr, hgtb, nullptr, ETb, nullptr, 4096, 4096, 256, 4096,
        S, S, S, 0, nullptr, nullptr, 0, dE, 4096, discT, S);

    // enh = (sum_e hg[n][e]*ET[c][e]) / degN[n] + ind   (f32 + bf16)
    mg<3,false,true,false><<<dim3(32,2,8), 256, 0, stream>>>(
        hgb, nullptr, ETb, nullptr, enhF, enhB, 4096, 256, 4096, 256,
        S, S, S, S, nullptr, dN, 4096, nullptr, 0, ind, S);

    // h = relu(enh @ W1^T + b1)
    mg<4,false,false,false><<<dim3(256,8,1), 256, 0, stream>>>(
        enhB, nullptr, w1b, nullptr, hB, nullptr, 256, 256, 256, 1024,
        0, 0, 0, 0, b1, nullptr, 0, nullptr, 0, nullptr, 0);

    // q = h @ W2^T + b2 + enh   (f32)
    mg<5,false,false,false><<<dim3(256,2,1), 256, 0, stream>>>(
        hB, nullptr, w2b, nullptr, qF, nullptr, 1024, 1024, 1024, 256,
        0, 0, 0, 0, b2, nullptr, 0, nullptr, 0, enhF, 0);

    ln_k<<<BN, 256, 0, stream>>>(qF, ln_g, ln_b, out);
}

// Round 9
// 633.681 us; speedup vs baseline: 4.7308x; 1.2331x over previous
//
#include <hip/hip_runtime.h>
#include <stdint.h>

// B=8, N=4096, D=256, F=1024.  MFMA 16x16x32 bf16, 128x128 tiles, 4 waves.
// hg bit-packed in both orientations (L3-resident aggregations).
// R7 (measured): LDS XOR-swizzle -> bank conflicts 1.68e7 -> 0; total 781us.
// R8: gram UNSPLIT (pure bf16, 1 MFMA/frag instead of 3).  Error analysis:
//     ~10k threshold flips/batch, propagated absmax contribution ~0.01 << 0.109.
//     prep_k drops lo-part computation/writes.

typedef unsigned short u16;
typedef __attribute__((ext_vector_type(8))) short bf16x8;
typedef __attribute__((ext_vector_type(4))) float f32x4;

#define GLDS(g, l) __builtin_amdgcn_global_load_lds((const __attribute__((address_space(1))) void*)(g), (__attribute__((address_space(3))) void*)(l), 16, 0, 0)

__device__ __forceinline__ float4 ld4(const float* p){ return *reinterpret_cast<const float4*>(p); }
__device__ __forceinline__ u16 f2bf(float f){
    union{float f;unsigned u;}x{f};
    unsigned r=(x.u+0x7FFFu+((x.u>>16)&1u))>>16; return (u16)r;
}
__device__ __forceinline__ float bf2f(u16 s){
    union{unsigned u;float f;}x{(unsigned)s<<16}; return x.f;
}
__device__ __forceinline__ unsigned pk2(unsigned v, int i){
    return (((v>>i)&1u)*0x3F80u) | (((v>>(i+1))&1u)*0x3F800000u);
}

// ---------------------------------------------------------------------------
// Unified MFMA GEMM.  C[i,j] = sum_k A[i,k]*B[k,j].
// LDS tile: [128 rows][4 chunks of 8 u16]; physical chunk = logical ^ ((row>>1)&3).
// ---------------------------------------------------------------------------
template<int EPI, bool SPLIT, bool ABITS, bool BBITS>
__global__ __launch_bounds__(256)
void mg(const u16* __restrict__ A, const u16* __restrict__ A2,
        const u16* __restrict__ Bt, const u16* __restrict__ B2,
        void* __restrict__ C, void* __restrict__ C2,
        int K, int lda, int ldb, int ldc,
        long long sA, long long sB, long long sC, long long sC2,
        const float* __restrict__ bias,
        const float* __restrict__ v1, long long sv1,
        const float* __restrict__ v2, long long sv2,
        const void* __restrict__ resid, long long sR)
{
    __shared__ u16 As[4096], Bs[4096];
    __shared__ u16 As2[SPLIT ? 4096 : 8], Bs2[SPLIT ? 4096 : 8];
    const int t = threadIdx.x, lane = t & 63, wv = t >> 6;
    const int i0 = blockIdx.x*128, j0 = blockIdx.y*128, z = blockIdx.z;
    const int wr = (wv>>1)*64, wc = (wv&1)*64;

    const u16* Az  = A  + (size_t)z*sA;
    const u16* Bz  = Bt + (size_t)z*sB;
    const u16* A2z = SPLIT ? A2 + (size_t)z*sA : nullptr;
    const u16* B2z = SPLIT ? B2 + (size_t)z*sB : nullptr;

    // staging geometry (GLDS path): lane -> LDS row lr, source chunk swizzled
    const int glr = lane >> 2;                       // row-within-16 per GLDS call
    const int gsc = (lane & 3) ^ ((glr >> 1) & 3);   // swizzled source chunk
    // fragment-read geometry: per-lane constant chunk offset
    const int frow = lane & 15;
    const int fcho = ((lane >> 4) ^ ((frow >> 1) & 3)) * 8;

    f32x4 zero4 = {0.f,0.f,0.f,0.f};
    f32x4 acc[4][4];
    #pragma unroll
    for (int m=0;m<4;++m)
        #pragma unroll
        for (int n=0;n<4;++n) acc[m][n] = zero4;

    for (int k0 = 0; k0 < K; k0 += 32) {
        if constexpr (ABITS) {
            const int row = t & 127, half = t >> 7, sw = (row>>1)&3;
            unsigned v = Az[(size_t)(i0+row)*lda + (k0>>4) + half];
            u16* base = As + row*32;
            uint4 w0, w1;
            w0.x=pk2(v,0);  w0.y=pk2(v,2);  w0.z=pk2(v,4);  w0.w=pk2(v,6);
            w1.x=pk2(v,8);  w1.y=pk2(v,10); w1.z=pk2(v,12); w1.w=pk2(v,14);
            *(uint4*)(base + ((2*half  )^sw)*8) = w0;
            *(uint4*)(base + ((2*half+1)^sw)*8) = w1;
        } else {
            #pragma unroll
            for (int q=0;q<2;++q) {
                const int lr = wv*32 + q*16 + glr;
                GLDS(Az + (size_t)(i0+lr)*lda + k0 + gsc*8, As + (wv*32 + q*16)*32);
            }
        }
        if constexpr (BBITS) {
            const int row = t & 127, half = t >> 7, sw = (row>>1)&3;
            unsigned v = Bz[(size_t)(j0+row)*ldb + (k0>>4) + half];
            u16* base = Bs + row*32;
            uint4 w0, w1;
            w0.x=pk2(v,0);  w0.y=pk2(v,2);  w0.z=pk2(v,4);  w0.w=pk2(v,6);
            w1.x=pk2(v,8);  w1.y=pk2(v,10); w1.z=pk2(v,12); w1.w=pk2(v,14);
            *(uint4*)(base + ((2*half  )^sw)*8) = w0;
            *(uint4*)(base + ((2*half+1)^sw)*8) = w1;
        } else {
            #pragma unroll
            for (int q=0;q<2;++q) {
                const int lr = wv*32 + q*16 + glr;
                GLDS(Bz + (size_t)(j0+lr)*ldb + k0 + gsc*8, Bs + (wv*32 + q*16)*32);
            }
        }
        if constexpr (SPLIT) {
            #pragma unroll
            for (int q=0;q<2;++q) {
                const int lr = wv*32 + q*16 + glr;
                GLDS(A2z + (size_t)(i0+lr)*lda + k0 + gsc*8, As2 + (wv*32 + q*16)*32);
                GLDS(B2z + (size_t)(j0+lr)*ldb + k0 + gsc*8, Bs2 + (wv*32 + q*16)*32);
            }
        }
        __syncthreads();

        bf16x8 fa[4], fb[4];
        #pragma unroll
        for (int m=0;m<4;++m) fa[m] = *(const bf16x8*)&As[(wr + m*16 + frow)*32 + fcho];
        #pragma unroll
        for (int n=0;n<4;++n) fb[n] = *(const bf16x8*)&Bs[(wc + n*16 + frow)*32 + fcho];
        if constexpr (SPLIT) {
            bf16x8 fa2[4], fb2[4];
            #pragma unroll
            for (int m=0;m<4;++m) fa2[m] = *(const bf16x8*)&As2[(wr + m*16 + frow)*32 + fcho];
            #pragma unroll
            for (int n=0;n<4;++n) fb2[n] = *(const bf16x8*)&Bs2[(wc + n*16 + frow)*32 + fcho];
            #pragma unroll
            for (int m=0;m<4;++m)
                #pragma unroll
                for (int n=0;n<4;++n) {
                    acc[m][n] = __builtin_amdgcn_mfma_f32_16x16x32_bf16(fa[m],  fb[n],  acc[m][n], 0,0,0);
                    acc[m][n] = __builtin_amdgcn_mfma_f32_16x16x32_bf16(fa[m],  fb2[n], acc[m][n], 0,0,0);
                    acc[m][n] = __builtin_amdgcn_mfma_f32_16x16x32_bf16(fa2[m], fb[n],  acc[m][n], 0,0,0);
                }
        } else {
            #pragma unroll
            for (int m=0;m<4;++m)
                #pragma unroll
                for (int n=0;n<4;++n)
                    acc[m][n] = __builtin_amdgcn_mfma_f32_16x16x32_bf16(fa[m], fb[n], acc[m][n], 0,0,0);
        }
        __syncthreads();
    }

    // ---- epilogue.  C/D frag: col=lane&15, row=(lane>>4)*4 + j
    const int cl = lane & 15, rg = lane >> 4;
    if constexpr (EPI == 1) {
        u16* hgb  = (u16*)C  + (size_t)z*sC;
        u16* hgtb = (u16*)C2 + (size_t)z*sC2;
        const float* v1z = v1 + (size_t)z*sv1;
        const float* v2z = v2 + (size_t)z*sv2;
        #pragma unroll
        for (int m=0;m<4;++m) {
            #pragma unroll
            for (int n=0;n<4;++n) {
                const int rb = i0 + wr + m*16;
                const int cb = j0 + wc + n*16;
                const float n2c = v2z[cb + cl];
                unsigned long long b0,b1,b2,b3;
                { float s = v1z[rb+rg*4+0] + n2c - 2.f*acc[m][n][0]; b0 = __ballot(s < 529.f); }
                { float s = v1z[rb+rg*4+1] + n2c - 2.f*acc[m][n][1]; b1 = __ballot(s < 529.f); }
                { float s = v1z[rb+rg*4+2] + n2c - 2.f*acc[m][n][2]; b2 = __ballot(s < 529.f); }
                { float s = v1z[rb+rg*4+3] + n2c - 2.f*acc[m][n][3]; b3 = __ballot(s < 529.f); }
                unsigned long long bsel = (cl&2) ? ((cl&1)? b3 : b2) : ((cl&1)? b1 : b0);
                if (cl < 4)
                    hgb[(size_t)(rb + rg*4 + cl)*ldc + (cb>>4)] = (u16)((bsel >> (rg*16)) & 0xFFFFull);
                if (rg == 0) {
                    unsigned tb = 0;
                    #pragma unroll
                    for (int k=0;k<16;++k) {
                        unsigned long long bb = (k&2) ? ((k&1)? b3:b2) : ((k&1)? b1:b0);
                        tb |= (unsigned)((bb >> ((k>>2)*16 + cl)) & 1ull) << k;
                    }
                    hgtb[(size_t)(cb + cl)*ldc + (rb>>4)] = (u16)tb;
                }
            }
        }
    } else {
        float* Cf  = (float*)C  + (size_t)z*sC;
        u16*   Cb  = (u16*)C    + (size_t)z*sC;
        u16*   C2b = (u16*)C2   + (size_t)z*sC2;
        const float* Rf = (const float*)resid + (size_t)z*sR;
        const u16*   Rb = (const u16*)resid   + (size_t)z*sR;
        const float* v1z = v1 ? v1 + (size_t)z*sv1 : nullptr;
        const float* v2z = v2 ? v2 + (size_t)z*sv2 : nullptr;
        #pragma unroll
        for (int m=0;m<4;++m) {
            #pragma unroll
            for (int n=0;n<4;++n) {
                const int cc = j0 + wc + n*16 + cl;
                #pragma unroll
                for (int j=0;j<4;++j) {
                    const int r = i0 + wr + m*16 + rg*4 + j;
                    const float v = acc[m][n][j];
                    if constexpr (EPI == 0) {
                        Cb[(size_t)r*ldc + cc] = f2bf(v + bias[r]);
                    } else if constexpr (EPI == 2) {
                        float d = v2z[cc]; float nm = d > 0.f ? 1.f/d : 0.f;
                        Cb[(size_t)r*ldc + cc] = f2bf(v*nm + bf2f(Rb[(size_t)r*ldc + cc]));
                    } else if constexpr (EPI == 3) {
                        float d = v1z[r]; float nm = d > 0.f ? 1.f/d : 0.f;
                        float o = v*nm + Rf[(size_t)r*ldc + cc];
                        Cf [(size_t)r*ldc + cc] = o;
                        C2b[(size_t)r*ldc + cc] = f2bf(o);
                    } else if constexpr (EPI == 4) {
                        float o = v + bias[cc];
                        Cb[(size_t)r*ldc + cc] = f2bf(o > 0.f ? o : 0.f);
                    } else {
                        Cf[(size_t)r*ldc + cc] = v + bias[cc] + Rf[(size_t)r*ldc + cc];
                    }
                }
            }
        }
    }
}

// ---- fused prep: bf16 convert of ind & disc + row squared-norms -----------
__global__ __launch_bounds__(256)
void prep_k(const float* __restrict__ ind, const float* __restrict__ disc,
            u16* __restrict__ ih, u16* __restrict__ dh,
            float* __restrict__ n1, float* __restrict__ n2, int rows)
{
    int wid = threadIdx.x >> 6, lane = threadIdx.x & 63;
    int r = blockIdx.x*4 + wid;
    const float* src; u16 *hi; float* dst; int rr;
    if (r < rows) { src = ind;  hi = ih; dst = n1; rr = r; }
    else          { src = disc; hi = dh; dst = n2; rr = r - rows; }
    size_t off = (size_t)rr*256 + lane*4;
    float4 v = ld4(src + off);
    ushort4 h;
    h.x = f2bf(v.x); h.y = f2bf(v.y); h.z = f2bf(v.z); h.w = f2bf(v.w);
    *(ushort4*)(hi+off) = h;
    float s = v.x*v.x + v.y*v.y + v.z*v.z + v.w*v.w;
    #pragma unroll
    for (int o=32;o;o>>=1) s += __shfl_down(s, o);
    if (lane == 0) dst[rr] = s;
}

// ---- weight bf16 conversion -----------------------------------------------
__global__ __launch_bounds__(256)
void cvtw_k(const float* __restrict__ wfc, const float* __restrict__ w1,
            const float* __restrict__ w2, u16* __restrict__ owfc,
            u16* __restrict__ ow1, u16* __restrict__ ow2)
{
    int i = blockIdx.x*256 + threadIdx.x;
    if (i < 65536)  owfc[i] = f2bf(wfc[i]);
    if (i < 262144) { ow1[i] = f2bf(w1[i]); ow2[i] = f2bf(w2[i]); }
}

// ---- disc [b][n][d] f32 -> discT [b][d][n] bf16 ---------------------------
__global__ __launch_bounds__(256)
void tr_k(const float* __restrict__ src, u16* __restrict__ dst)
{
    __shared__ float tl[64][65];
    const int b = blockIdx.z, n0 = blockIdx.x*64, d0 = blockIdx.y*64;
    const float* s = src + (size_t)b*1048576;
    u16* o = dst + (size_t)b*1048576;
    const int tx = threadIdx.x & 15, ty = threadIdx.x >> 4;
    #pragma unroll
    for (int it=0; it<4; ++it) {
        int r = ty + it*16;
        float4 v = ld4(s + (size_t)(n0+r)*256 + d0 + tx*4);
        tl[r][tx*4+0]=v.x; tl[r][tx*4+1]=v.y; tl[r][tx*4+2]=v.z; tl[r][tx*4+3]=v.w;
    }
    __syncthreads();
    #pragma unroll
    for (int it=0; it<4; ++it) {
        int d = ty + it*16;
        ushort4 w;
        w.x = f2bf(tl[tx*4+0][d]); w.y = f2bf(tl[tx*4+1][d]);
        w.z = f2bf(tl[tx*4+2][d]); w.w = f2bf(tl[tx*4+3][d]);
        *(ushort4*)(o + (size_t)(d0+d)*4096 + n0 + tx*4) = w;
    }
}

// ---- degree = popcount of a bit-row ---------------------------------------
__global__ __launch_bounds__(256)
void popc_k(const u16* __restrict__ bits, float* __restrict__ deg)
{
    int wv = threadIdx.x >> 6, lane = threadIdx.x & 63;
    size_t row = (size_t)blockIdx.x*4 + wv;
    const unsigned* p = (const unsigned*)(bits + row*256);
    int s = __popc(p[lane]) + __popc(p[lane+64]);
    #pragma unroll
    for (int o=32;o;o>>=1) s += __shfl_down(s, o);
    if (lane == 0) deg[row] = (float)s;
}

// ---- LayerNorm over D=256 -------------------------------------------------
__global__ __launch_bounds__(256)
void ln_k(const float* __restrict__ q, const float* __restrict__ g,
          const float* __restrict__ bta, float* __restrict__ out)
{
    size_t row = blockIdx.x;
    int t = threadIdx.x;
    float x = q[row*256 + t];
    float s1 = x, s2 = x*x;
    int lane = t & 63, wid = t >> 6;
    #pragma unroll
    for (int o=32;o;o>>=1) { s1 += __shfl_down(s1,o); s2 += __shfl_down(s2,o); }
    __shared__ float a1[4], a2[4];
    if (lane == 0) { a1[wid]=s1; a2[wid]=s2; }
    __syncthreads();
    s1 = a1[0]+a1[1]+a1[2]+a1[3];
    s2 = a2[0]+a2[1]+a2[2]+a2[3];
    float mu  = s1 * (1.f/256.f);
    float var = s2 * (1.f/256.f) - mu*mu;
    float r = rsqrtf(var + 1e-5f);
    out[row*256 + t] = (x - mu) * r * g[t] + bta[t];
}

extern "C" void kernel_launch(void* const* d_in, const int* in_sizes, int n_in,
                              void* d_out, int out_size, void* d_ws, size_t ws_size,
                              hipStream_t stream)
{
    const float* disc = (const float*)d_in[0];
    const float* ind  = (const float*)d_in[1];
    const float* W_fc = (const float*)d_in[2];
    const float* b_fc = (const float*)d_in[3];
    const float* W1   = (const float*)d_in[4];
    const float* b1   = (const float*)d_in[5];
    const float* W2   = (const float*)d_in[6];
    const float* b2   = (const float*)d_in[7];
    const float* ln_g = (const float*)d_in[8];
    const float* ln_b = (const float*)d_in[9];
    float* out = (float*)d_out;

    char* ws = (char*)d_ws;
    u16* hgb   = (u16*)(ws + 0);           // hg  bits [b][n][256ch]   16.78MB
    u16* hgtb  = (u16*)(ws + 16777216);    // hgT bits [b][m][256ch]   16.78MB
    u16* ETb   = (u16*)(ws + 33554432);    // E^T bf16 [b][256][4096]  16.78MB
    u16* ih    = (u16*)(ws + 50331648);    // ind bf16                 16.78MB
    // + 67108864: free (was ind-lo)                                   16.78MB
    u16* dh    = (u16*)(ws + 83886080);    // disc bf16                16.78MB
    // +100663296: free (was disc-lo)                                  16.78MB
    u16* discT = (u16*)(ws + 117440512);
    u16* XTb   = (u16*)(ws + 134217728);
    float* enhF= (float*)(ws + 150994944); // enh f32 [BN][256]        33.55MB
    u16* enhB  = (u16*)(ws + 184549376);
    u16* wfcb  = (u16*)(ws + 201326592);
    u16* w1b   = (u16*)(ws + 201457664);
    u16* w2b   = (u16*)(ws + 201981952);
    float* n1  = (float*)(ws + 202506240);
    float* n2  = (float*)(ws + 202637312);
    float* dN  = (float*)(ws + 202768384);
    float* dE  = (float*)(ws + 202899456);
    u16* hB    = (u16*)(ws + 83886080);    // h bf16 aliases dh..XTb (dead)
    float* qF  = (float*)(ws + 50331648);  // q f32 aliases ih + free slot (dead)

    const int BN = 32768;
    const long long S = 1048576;

    prep_k<<<16384, 256, 0, stream>>>(ind, disc, ih, dh, n1, n2, BN);
    cvtw_k<<<1024, 256, 0, stream>>>(W_fc, W1, W2, wfcb, w1b, w2b);
    tr_k<<<dim3(64,4,8), 256, 0, stream>>>(disc, discT);

    // gram (pure bf16, 1 MFMA/frag): hg = bit-packed both orientations
    mg<1,false,false,false><<<dim3(32,32,8), 256, 0, stream>>>(
        ih, nullptr, dh, nullptr, hgb, hgtb, 256, 256, 256, 256,
        S, S, S, S, nullptr, n1, 4096, n2, 4096, nullptr, 0);

    popc_k<<<8192, 256, 0, stream>>>(hgb,  dN);
    popc_k<<<8192, 256, 0, stream>>>(hgtb, dE);

    // XT[b][c][n] = sum_d W_fc[c,d]*ind[b,n,d] + b_fc[c]
    mg<0,false,false,false><<<dim3(2,32,8), 256, 0, stream>>>(
        wfcb, nullptr, ih, nullptr, XTb, nullptr, 256, 256, 256, 4096,
        0, S, S, 0, b_fc, nullptr, 0, nullptr, 0, nullptr, 0);

    // ET[b][c][e] = (sum_n XT[c][n]*hgT[e][n]) / degE[e] + discT[c][e]
    mg<2,false,false,true><<<dim3(2,32,8), 256, 0, stream>>>(
        XTb, nullptr, hgtb, nullptr, ETb, nullptr, 4096, 4096, 256, 4096,
        S, S, S, 0, nullptr, nullptr, 0, dE, 4096, discT, S);

    // enh = (sum_e hg[n][e]*ET[c][e]) / degN[n] + ind   (f32 + bf16)
    mg<3,false,true,false><<<dim3(32,2,8), 256, 0, stream>>>(
        hgb, nullptr, ETb, nullptr, enhF, enhB, 4096, 256, 4096, 256,
        S, S, S, S, nullptr, dN, 4096, nullptr, 0, ind, S);

    // h = relu(enh @ W1^T + b1)
    mg<4,false,false,false><<<dim3(256,8,1), 256, 0, stream>>>(
        enhB, nullptr, w1b, nullptr, hB, nullptr, 256, 256, 256, 1024,
        0, 0, 0, 0, b1, nullptr, 0, nullptr, 0, nullptr, 0);

    // q = h @ W2^T + b2 + enh   (f32)
    mg<5,false,false,false><<<dim3(256,2,1), 256, 0, stream>>>(
        hB, nullptr, w2b, nullptr, qF, nullptr, 1024, 1024, 1024, 256,
        0, 0, 0, 0, b2, nullptr, 0, nullptr, 0, enhF, 0);

    ln_k<<<BN, 256, 0, stream>>>(qF, ln_g, ln_b, out);
}